// Round 7
// baseline (203.455 us; speedup 1.0000x reference)
//
#include <hip/hip_runtime.h>
#include <stdint.h>

#define BHALF 4096
#define NROWS 8192
#define DDIM  512
#define KNEG  8190.0f

#define BM   128
#define BK   64
#define KIT  (DDIM / BK)               // 8 K-iterations
#define NTIL 64                        // 8192 / 128
#define TBLK (NTIL * (NTIL + 1) / 2)   // 2080 upper-triangle tiles
#define RBLK 32                        // finalize blocks

typedef short v8s __attribute__((ext_vector_type(8)));   // 8 bf16 MFMA A/B frag
typedef float v4f __attribute__((ext_vector_type(4)));   // MFMA C/D frag

static __device__ inline float bf2f(uint32_t u) {
    union { uint32_t i; float f; } c; c.i = u << 16; return c.f;
}
static __device__ inline uint32_t f2bf(float f) {
    union { float f; uint32_t i; } c; c.f = f;
    return (c.i + 0x7fffu + ((c.i >> 16) & 1u)) >> 16;
}

// per-wave dtype test: bf16 data -> low-half exponent fields clustered; fp32 -> uniform
static __device__ inline int wave_is_f32(uint32_t w) {
    uint32_t e = (w >> 7) & 0xFFu;
    return __popcll(__ballot(e < 100u || e > 140u)) > 16;
}

// async global->LDS, 16 B per lane; LDS dest = wave-uniform base + lane*16
#define GLL16(gp, lp)                                                         \
    __builtin_amdgcn_global_load_lds(                                         \
        (__attribute__((address_space(1))) void*)(gp),                        \
        (__attribute__((address_space(3))) void*)(lp), 16, 0, 0)

// -------- Kernel 1: per-row inverse L2 norm (wave per row) + zero counter --------
__global__ __launch_bounds__(256) void rownorm_kernel(
    const void* __restrict__ o1, const void* __restrict__ o2,
    float* __restrict__ rn, unsigned int* __restrict__ cnt)
{
    if (blockIdx.x == 0 && threadIdx.x == 0) cnt[0] = 0u;
    int wave = threadIdx.x >> 6, lane = threadIdx.x & 63;
    int row = blockIdx.x * 4 + wave;
    const uint16_t* sb = (row < BHALF)
        ? (const uint16_t*)o1 + (size_t)row * DDIM
        : (const uint16_t*)o2 + (size_t)(row - BHALF) * DDIM;
    uint4 v = ((const uint4*)sb)[lane];            // row as bf16-interp (1 KB)
    float ss;
    if (!wave_is_f32(v.x)) {
        float a0 = bf2f(v.x & 0xffffu), a1 = bf2f(v.x >> 16);
        float a2 = bf2f(v.y & 0xffffu), a3 = bf2f(v.y >> 16);
        float a4 = bf2f(v.z & 0xffffu), a5 = bf2f(v.z >> 16);
        float a6 = bf2f(v.w & 0xffffu), a7 = bf2f(v.w >> 16);
        ss = a0*a0 + a1*a1 + a2*a2 + a3*a3 + a4*a4 + a5*a5 + a6*a6 + a7*a7;
    } else {
        const float* s = (row < BHALF)
            ? (const float*)o1 + (size_t)row * DDIM
            : (const float*)o2 + (size_t)(row - BHALF) * DDIM;
        float4 a = ((const float4*)s)[2 * lane];
        float4 b = ((const float4*)s)[2 * lane + 1];
        ss = a.x*a.x + a.y*a.y + a.z*a.z + a.w*a.w
           + b.x*b.x + b.y*b.y + b.z*b.z + b.w*b.w;
    }
    for (int m = 32; m; m >>= 1) ss += __shfl_xor(ss, m);
    if (lane == 0) rn[row] = rsqrtf(ss);
}

// -------- Kernel 2: upper-triangle Gram tiles + fused exp sums, no atomics --------
// 2080 tiles, 256 threads, BK=64 (8 iters). LDS row = 128 B (8 x 16B slots);
// chunk c of row r stored at slot (c+r)&7 -> DMA lane-contiguous, ds_read_b128 2-way free.
__global__ __launch_bounds__(256, 4) void SupCon_hcl_49323404427556_kernel(
    const void* __restrict__ o1, const void* __restrict__ o2,
    const float* __restrict__ rn,
    float* __restrict__ pden, float* __restrict__ pnum, float* __restrict__ cpos)
{
    __shared__ alignas(16) uint16_t la[BM * BK];   // 16 KiB
    __shared__ alignas(16) uint16_t lb[BM * BK];   // 16 KiB
    __shared__ float rnA[BM], rnB[BM];
    __shared__ float s_dr[BM][2], s_nr[BM][2], s_dc[BM][2], s_nc[BM][2];  // 4 KiB

    int tid  = threadIdx.x;
    int wave = tid >> 6, lane = tid & 63;
    int quad = lane >> 4, l16 = lane & 15;
    int wrow = (wave >> 1) * 64, wcol = (wave & 1) * 64;

    // ---- triangular decode: t -> (bi, bj), bj >= bi ----
    int t = blockIdx.x;
    int bi = (int)(64.5f - sqrtf(64.5f * 64.5f - 2.0f * (float)t));
    while (bi > 0 && (64 * bi - (bi * (bi - 1)) / 2) > t) --bi;
    while ((64 * (bi + 1) - ((bi + 1) * bi) / 2) <= t) ++bi;
    int bj = bi + (t - (64 * bi - (bi * (bi - 1)) / 2));
    int i0 = bi * BM, j0 = bj * BM;
    bool diag = (bi == bj);

    if (tid < BM) rnA[tid] = rn[i0 + tid];
    else          rnB[tid - BM] = rn[j0 + (tid - BM)];

    const uint16_t *A16, *B16; const float *A32, *B32;
    if (i0 < BHALF) { A16 = (const uint16_t*)o1 + (size_t)i0 * DDIM;
                      A32 = (const float*)o1    + (size_t)i0 * DDIM; }
    else            { A16 = (const uint16_t*)o2 + (size_t)(i0 - BHALF) * DDIM;
                      A32 = (const float*)o2    + (size_t)(i0 - BHALF) * DDIM; }
    if (j0 < BHALF) { B16 = (const uint16_t*)o1 + (size_t)j0 * DDIM;
                      B32 = (const float*)o1    + (size_t)j0 * DDIM; }
    else            { B16 = (const uint16_t*)o2 + (size_t)(j0 - BHALF) * DDIM;
                      B32 = (const float*)o2    + (size_t)(j0 - BHALF) * DDIM; }

    int isF32 = wave_is_f32(((const uint32_t*)A16)[lane]);   // wave-uniform

    v4f acc[4][4];
    v4f z = {0.f, 0.f, 0.f, 0.f};
    #pragma unroll
    for (int a = 0; a < 4; ++a)
        #pragma unroll
        for (int b = 0; b < 4; ++b) acc[a][b] = z;

    // ---- staging geometry: wave w stages rows [32w,32w+32), 4 dma-instrs of 8 rows ----
    int rl   = lane >> 3;                 // 0..7 row within 8-row group
    int slot = lane & 7;                  // 16B slot within 128B row
    int chk  = (slot - rl) & 7;           // source chunk (row mod 8 == rl)
    const uint16_t* gA = A16 + (size_t)(32 * wave + rl) * DDIM + chk * 8;
    const uint16_t* gB = B16 + (size_t)(32 * wave + rl) * DDIM + chk * 8;

    const uint16_t* lbp = diag ? la : lb;

    for (int kb = 0; kb < KIT; ++kb) {
        __syncthreads();
        if (!isF32) {
            #pragma unroll
            for (int q = 0; q < 4; ++q) {
                GLL16(gA + kb * BK + (size_t)(8 * q) * DDIM, &la[(32 * wave + 8 * q) * BK]);
                if (!diag)
                    GLL16(gB + kb * BK + (size_t)(8 * q) * DDIM, &lb[(32 * wave + 8 * q) * BK]);
            }
        } else {
            #pragma unroll
            for (int q = 0; q < 4; ++q) {
                int r = 32 * wave + 8 * q + rl;
                const float* pa = A32 + (size_t)r * DDIM + kb * BK + chk * 8;
                uint4 wa;
                wa.x = f2bf(pa[0]) | (f2bf(pa[1]) << 16);
                wa.y = f2bf(pa[2]) | (f2bf(pa[3]) << 16);
                wa.z = f2bf(pa[4]) | (f2bf(pa[5]) << 16);
                wa.w = f2bf(pa[6]) | (f2bf(pa[7]) << 16);
                *(uint4*)(&la[r * BK + slot * 8]) = wa;
                if (!diag) {
                    const float* pb = B32 + (size_t)r * DDIM + kb * BK + chk * 8;
                    uint4 wb;
                    wb.x = f2bf(pb[0]) | (f2bf(pb[1]) << 16);
                    wb.y = f2bf(pb[2]) | (f2bf(pb[3]) << 16);
                    wb.z = f2bf(pb[4]) | (f2bf(pb[5]) << 16);
                    wb.w = f2bf(pb[6]) | (f2bf(pb[7]) << 16);
                    *(uint4*)(&lb[r * BK + slot * 8]) = wb;
                }
            }
        }
        __syncthreads();

        #pragma unroll
        for (int ks = 0; ks < 2; ++ks) {
            v8s af[4], bfr[4];
            #pragma unroll
            for (int tt = 0; tt < 4; ++tt) {
                int ra = wrow + 16 * tt + l16;
                int rb = wcol + 16 * tt + l16;
                af[tt]  = *(const v8s*)(&la [ra * BK + ((ks * 4 + quad + l16) & 7) * 8]);
                bfr[tt] = *(const v8s*)(&lbp[rb * BK + ((ks * 4 + quad + l16) & 7) * 8]);
            }
            #pragma unroll
            for (int mt = 0; mt < 4; ++mt)
                #pragma unroll
                for (int nt = 0; nt < 4; ++nt)
                    acc[mt][nt] = __builtin_amdgcn_mfma_f32_16x16x32_bf16(
                        af[mt], bfr[nt], acc[mt][nt], 0, 0, 0);
        }
    }

    // ---- e = exp(d * rn_i * rn_j) in place ----
    #pragma unroll
    for (int mt = 0; mt < 4; ++mt) {
        #pragma unroll
        for (int nt = 0; nt < 4; ++nt) {
            float rj = rnB[wcol + 16 * nt + l16];
            #pragma unroll
            for (int r = 0; r < 4; ++r) {
                float ri = rnA[wrow + 16 * mt + quad * 4 + r];
                acc[mt][nt][r] = __expf(acc[mt][nt][r] * ri * rj);
            }
        }
    }

    // ---- row pass: per-wave half-row sums -> LDS; partner -> cpos[gi] ----
    #pragma unroll
    for (int mt = 0; mt < 4; ++mt) {
        #pragma unroll
        for (int r = 0; r < 4; ++r) {
            int gil = wrow + 16 * mt + quad * 4 + r;
            int gi = i0 + gil;
            int partner = gi ^ BHALF;
            float pd = 0.f, pn = 0.f;
            #pragma unroll
            for (int nt = 0; nt < 4; ++nt) {
                int gj = j0 + wcol + 16 * nt + l16;
                float e = acc[mt][nt][r];
                if (gj == partner) cpos[gi] = e * e;
                if (gj != gi && gj != partner) { pd += e; pn += e * e * e; }
            }
            #pragma unroll
            for (int m = 1; m < 16; m <<= 1) {
                pd += __shfl_xor(pd, m);
                pn += __shfl_xor(pn, m);
            }
            if (l16 == 0) { s_dr[gil][wcol >> 6] = pd; s_nr[gil][wcol >> 6] = pn; }
        }
    }

    // ---- col pass (off-diagonal): per-wave half-col sums -> LDS ----
    if (!diag) {
        #pragma unroll
        for (int nt = 0; nt < 4; ++nt) {
            int gjl = wcol + 16 * nt + l16;
            int gj = j0 + gjl;
            int pj = gj ^ BHALF;
            float cd = 0.f, cn = 0.f;
            #pragma unroll
            for (int mt = 0; mt < 4; ++mt) {
                #pragma unroll
                for (int r = 0; r < 4; ++r) {
                    int gi = i0 + wrow + 16 * mt + quad * 4 + r;
                    float e = acc[mt][nt][r];
                    if (gi == pj) cpos[gj] = e * e;
                    else { cd += e; cn += e * e * e; }
                }
            }
            cd += __shfl_xor(cd, 16); cn += __shfl_xor(cn, 16);
            cd += __shfl_xor(cd, 32); cn += __shfl_xor(cn, 32);
            if (quad == 0) { s_dc[gjl][wrow >> 6] = cd; s_nc[gjl][wrow >> 6] = cn; }
        }
    }

    __syncthreads();
    if (tid < BM) {
        pden[(size_t)bj * NROWS + i0 + tid] = s_dr[tid][0] + s_dr[tid][1];
        pnum[(size_t)bj * NROWS + i0 + tid] = s_nr[tid][0] + s_nr[tid][1];
        if (!diag) {
            pden[(size_t)bi * NROWS + j0 + tid] = s_dc[tid][0] + s_dc[tid][1];
            pnum[(size_t)bi * NROWS + j0 + tid] = s_nc[tid][0] + s_nc[tid][1];
        }
    }
}

// -------- Kernel 3: fold partials -> loss; last block reduces to scalar --------
__global__ __launch_bounds__(256) void finalize_kernel(
    const float* __restrict__ pden, const float* __restrict__ pnum,
    const float* __restrict__ cpos, float* __restrict__ bpart,
    unsigned int* __restrict__ cnt, float* __restrict__ out)
{
    int i = blockIdx.x * 256 + threadIdx.x;    // RBLK*256 == NROWS
    float den = 0.f, num = 0.f;
    #pragma unroll 8
    for (int x = 0; x < NTIL; ++x) {
        den += pden[(size_t)x * NROWS + i];
        num += pnum[(size_t)x * NROWS + i];
    }
    float s = logf(1.0f + KNEG * (num / den) / cpos[i]);
    for (int m = 32; m; m >>= 1) s += __shfl_xor(s, m);
    __shared__ float wsum[4];
    if ((threadIdx.x & 63) == 0) wsum[threadIdx.x >> 6] = s;
    __syncthreads();
    if (threadIdx.x == 0) {
        atomicExch(&bpart[blockIdx.x], wsum[0] + wsum[1] + wsum[2] + wsum[3]);
        __threadfence();
        unsigned int old = atomicAdd(cnt, 1u);
        if (old == RBLK - 1) {                 // last block: reduce via atomic loads
            float tot = 0.f;
            for (int b = 0; b < RBLK; ++b) tot += atomicAdd(&bpart[b], 0.0f);
            out[0] = tot / (float)NROWS;
        }
    }
}

extern "C" void kernel_launch(void* const* d_in, const int* in_sizes, int n_in,
                              void* d_out, int out_size, void* d_ws, size_t ws_size,
                              hipStream_t stream)
{
    const void* o1 = d_in[1];
    const void* o2 = d_in[2];

    // ws: pden 2MB | pnum 2MB | rn 32KB | cpos 32KB | bpart | cnt
    float* pden = (float*)d_ws;
    float* pnum = pden + (size_t)NTIL * NROWS;
    float* rn   = pnum + (size_t)NTIL * NROWS;
    float* cpos = rn + NROWS;
    float* bpart= cpos + NROWS;
    unsigned int* cnt = (unsigned int*)(bpart + RBLK);

    rownorm_kernel<<<NROWS / 4, 256, 0, stream>>>(o1, o2, rn, cnt);
    SupCon_hcl_49323404427556_kernel<<<TBLK, 256, 0, stream>>>(o1, o2, rn, pden, pnum, cpos);
    finalize_kernel<<<RBLK, 256, 0, stream>>>(pden, pnum, cpos, bpart, cnt, (float*)d_out);
}

// Round 8
// 200.654 us; speedup vs baseline: 1.0140x; 1.0140x over previous
//
#include <hip/hip_runtime.h>
#include <stdint.h>

#define BHALF 4096
#define NROWS 8192
#define DDIM  512
#define KNEG  8190.0f

#define BM   256                       // tile edge
#define BK   32
#define KIT  (DDIM / BK)               // 16 K-iterations
#define NTIL 32                        // 8192 / 256
#define TBLK (NTIL * (NTIL + 1) / 2)   // 528 upper-triangle tiles
#define RBLK 32                        // finalize blocks

typedef short v8s __attribute__((ext_vector_type(8)));   // 8 bf16 MFMA A/B frag
typedef float v4f __attribute__((ext_vector_type(4)));   // MFMA C/D frag

static __device__ inline float bf2f(uint32_t u) {
    union { uint32_t i; float f; } c; c.i = u << 16; return c.f;
}
static __device__ inline uint32_t f2bf(float f) {
    union { float f; uint32_t i; } c; c.f = f;
    return (c.i + 0x7fffu + ((c.i >> 16) & 1u)) >> 16;
}

// per-wave dtype test: bf16 data -> low-half exponent fields clustered; fp32 -> uniform
static __device__ inline int wave_is_f32(uint32_t w) {
    uint32_t e = (w >> 7) & 0xFFu;
    return __popcll(__ballot(e < 100u || e > 140u)) > 16;
}

// async global->LDS, 16 B per lane; LDS dest = wave-uniform base + lane*16
#define GLL16(gp, lp)                                                         \
    __builtin_amdgcn_global_load_lds(                                         \
        (__attribute__((address_space(1))) void*)(gp),                        \
        (__attribute__((address_space(3))) void*)(lp), 16, 0, 0)

// -------- Kernel 1: per-row inverse L2 norm (wave per row) + zero counter --------
__global__ __launch_bounds__(256) void rownorm_kernel(
    const void* __restrict__ o1, const void* __restrict__ o2,
    float* __restrict__ rn, unsigned int* __restrict__ cnt)
{
    if (blockIdx.x == 0 && threadIdx.x == 0) cnt[0] = 0u;
    int wave = threadIdx.x >> 6, lane = threadIdx.x & 63;
    int row = blockIdx.x * 4 + wave;
    const uint16_t* sb = (row < BHALF)
        ? (const uint16_t*)o1 + (size_t)row * DDIM
        : (const uint16_t*)o2 + (size_t)(row - BHALF) * DDIM;
    uint4 v = ((const uint4*)sb)[lane];
    float ss;
    if (!wave_is_f32(v.x)) {
        float a0 = bf2f(v.x & 0xffffu), a1 = bf2f(v.x >> 16);
        float a2 = bf2f(v.y & 0xffffu), a3 = bf2f(v.y >> 16);
        float a4 = bf2f(v.z & 0xffffu), a5 = bf2f(v.z >> 16);
        float a6 = bf2f(v.w & 0xffffu), a7 = bf2f(v.w >> 16);
        ss = a0*a0 + a1*a1 + a2*a2 + a3*a3 + a4*a4 + a5*a5 + a6*a6 + a7*a7;
    } else {
        const float* s = (row < BHALF)
            ? (const float*)o1 + (size_t)row * DDIM
            : (const float*)o2 + (size_t)(row - BHALF) * DDIM;
        float4 a = ((const float4*)s)[2 * lane];
        float4 b = ((const float4*)s)[2 * lane + 1];
        ss = a.x*a.x + a.y*a.y + a.z*a.z + a.w*a.w
           + b.x*b.x + b.y*b.y + b.z*b.z + b.w*b.w;
    }
    for (int m = 32; m; m >>= 1) ss += __shfl_xor(ss, m);
    if (lane == 0) rn[row] = rsqrtf(ss);
}

// -------- Kernel 2: 256x256 upper-triangle Gram tiles + fused exp sums ----------
// 528 tiles, 1024 threads (16 waves, 4x4 wave grid, 64x64 out per wave), BK=32.
// LDS row = 64 B (4 x 16B slots); chunk c of row r at slot (c + (r>>1)) & 3
// (r6-proven swizzle: 0 bank conflicts; DMA lane order preserved).
// C/D layout: col = lane&15, row = quad*4 + reg.
__global__ __launch_bounds__(1024, 4) void SupCon_hcl_49323404427556_kernel(
    const void* __restrict__ o1, const void* __restrict__ o2,
    const float* __restrict__ rn,
    float* __restrict__ pden, float* __restrict__ pnum, float* __restrict__ cpos)
{
    __shared__ alignas(16) uint16_t la[BM * BK];   // 16 KiB
    __shared__ alignas(16) uint16_t lb[BM * BK];   // 16 KiB
    __shared__ float rnA[BM], rnB[BM];             // 2 KiB
    __shared__ float s_dr[BM][4], s_nr[BM][4], s_dc[BM][4], s_nc[BM][4];  // 16 KiB

    int tid  = threadIdx.x;
    int wave = tid >> 6, lane = tid & 63;
    int quad = lane >> 4, l16 = lane & 15;
    int wm = wave >> 2, wn = wave & 3;             // wave tile position (M,N)

    // ---- triangular decode: t -> (bi, bj), bj >= bi, NTIL=32 ----
    int t = blockIdx.x;
    int bi = (int)(32.5f - sqrtf(32.5f * 32.5f - 2.0f * (float)t));
    while (bi > 0 && (32 * bi - (bi * (bi - 1)) / 2) > t) --bi;
    while ((32 * (bi + 1) - ((bi + 1) * bi) / 2) <= t) ++bi;
    int bj = bi + (t - (32 * bi - (bi * (bi - 1)) / 2));
    int i0 = bi * BM, j0 = bj * BM;
    bool diag = (bi == bj);

    if (tid < BM)            rnA[tid] = rn[i0 + tid];
    else if (tid < 2 * BM)   rnB[tid - BM] = rn[j0 + (tid - BM)];

    const uint16_t *A16, *B16; const float *A32, *B32;
    if (i0 < BHALF) { A16 = (const uint16_t*)o1 + (size_t)i0 * DDIM;
                      A32 = (const float*)o1    + (size_t)i0 * DDIM; }
    else            { A16 = (const uint16_t*)o2 + (size_t)(i0 - BHALF) * DDIM;
                      A32 = (const float*)o2    + (size_t)(i0 - BHALF) * DDIM; }
    if (j0 < BHALF) { B16 = (const uint16_t*)o1 + (size_t)j0 * DDIM;
                      B32 = (const float*)o1    + (size_t)j0 * DDIM; }
    else            { B16 = (const uint16_t*)o2 + (size_t)(j0 - BHALF) * DDIM;
                      B32 = (const float*)o2    + (size_t)(j0 - BHALF) * DDIM; }

    int isF32 = wave_is_f32(((const uint32_t*)A16)[lane]);   // wave-uniform

    v4f acc[4][4];
    v4f z = {0.f, 0.f, 0.f, 0.f};
    #pragma unroll
    for (int a = 0; a < 4; ++a)
        #pragma unroll
        for (int b = 0; b < 4; ++b) acc[a][b] = z;

    // ---- staging: wave w stages rows [16w,16w+16), 1 DMA per matrix per iter ----
    int rl   = lane >> 2;                 // 0..15 row within group
    int slot = lane & 3;                  // 16B slot within 64B row
    int rA   = 16 * wave + rl;            // 0..255
    int chk  = (slot - (rA >> 1)) & 3;    // swizzled source chunk
    const uint16_t* gA = A16 + (size_t)rA * DDIM + chk * 8;
    const uint16_t* gB = B16 + (size_t)rA * DDIM + chk * 8;
    uint16_t* ldsA = &la[(16 * wave) * BK];
    uint16_t* ldsB = &lb[(16 * wave) * BK];

    const uint16_t* lbp = diag ? la : lb;
    int sfrag = (quad + (l16 >> 1)) & 3;  // read-side swizzled slot

    for (int kb = 0; kb < KIT; ++kb) {
        __syncthreads();
        if (!isF32) {
            GLL16(gA + kb * BK, ldsA);
            if (!diag) GLL16(gB + kb * BK, ldsB);
        } else {
            const float* pa = A32 + (size_t)rA * DDIM + kb * BK + chk * 8;
            uint4 wa;
            wa.x = f2bf(pa[0]) | (f2bf(pa[1]) << 16);
            wa.y = f2bf(pa[2]) | (f2bf(pa[3]) << 16);
            wa.z = f2bf(pa[4]) | (f2bf(pa[5]) << 16);
            wa.w = f2bf(pa[6]) | (f2bf(pa[7]) << 16);
            *(uint4*)(&la[rA * BK + slot * 8]) = wa;
            if (!diag) {
                const float* pb = B32 + (size_t)rA * DDIM + kb * BK + chk * 8;
                uint4 wb;
                wb.x = f2bf(pb[0]) | (f2bf(pb[1]) << 16);
                wb.y = f2bf(pb[2]) | (f2bf(pb[3]) << 16);
                wb.z = f2bf(pb[4]) | (f2bf(pb[5]) << 16);
                wb.w = f2bf(pb[6]) | (f2bf(pb[7]) << 16);
                *(uint4*)(&lb[rA * BK + slot * 8]) = wb;
            }
        }
        __syncthreads();

        v8s af[4], bfr[4];
        #pragma unroll
        for (int tt = 0; tt < 4; ++tt) {
            int ra = 64 * wm + 16 * tt + l16;
            int rb = 64 * wn + 16 * tt + l16;
            af[tt]  = *(const v8s*)(&la [ra * BK + sfrag * 8]);
            bfr[tt] = *(const v8s*)(&lbp[rb * BK + sfrag * 8]);
        }
        #pragma unroll
        for (int mt = 0; mt < 4; ++mt)
            #pragma unroll
            for (int nt = 0; nt < 4; ++nt)
                acc[mt][nt] = __builtin_amdgcn_mfma_f32_16x16x32_bf16(
                    af[mt], bfr[nt], acc[mt][nt], 0, 0, 0);
    }

    // ---- e = exp(d * rn_i * rn_j) in place ----
    #pragma unroll
    for (int mt = 0; mt < 4; ++mt) {
        #pragma unroll
        for (int nt = 0; nt < 4; ++nt) {
            float rj = rnB[64 * wn + 16 * nt + l16];
            #pragma unroll
            for (int r = 0; r < 4; ++r) {
                float ri = rnA[64 * wm + 16 * mt + quad * 4 + r];
                acc[mt][nt][r] = __expf(acc[mt][nt][r] * ri * rj);
            }
        }
    }

    // ---- row pass: per-wave quarter-row sums -> LDS; partner -> cpos[gi] ----
    #pragma unroll
    for (int mt = 0; mt < 4; ++mt) {
        #pragma unroll
        for (int r = 0; r < 4; ++r) {
            int gil = 64 * wm + 16 * mt + quad * 4 + r;     // 0..255
            int gi = i0 + gil;
            int partner = gi ^ BHALF;
            float pd = 0.f, pn = 0.f;
            #pragma unroll
            for (int nt = 0; nt < 4; ++nt) {
                int gj = j0 + 64 * wn + 16 * nt + l16;
                float e = acc[mt][nt][r];
                if (gj == partner) cpos[gi] = e * e;
                if (gj != gi && gj != partner) { pd += e; pn += e * e * e; }
            }
            #pragma unroll
            for (int m = 1; m < 16; m <<= 1) {
                pd += __shfl_xor(pd, m);
                pn += __shfl_xor(pn, m);
            }
            if (l16 == 0) { s_dr[gil][wn] = pd; s_nr[gil][wn] = pn; }
        }
    }

    // ---- col pass (off-diagonal): per-wave quarter-col sums -> LDS ----
    if (!diag) {
        #pragma unroll
        for (int nt = 0; nt < 4; ++nt) {
            int gjl = 64 * wn + 16 * nt + l16;              // 0..255
            int gj = j0 + gjl;
            int pj = gj ^ BHALF;
            float cd = 0.f, cn = 0.f;
            #pragma unroll
            for (int mt = 0; mt < 4; ++mt) {
                #pragma unroll
                for (int r = 0; r < 4; ++r) {
                    int gi = i0 + 64 * wm + 16 * mt + quad * 4 + r;
                    float e = acc[mt][nt][r];
                    if (gi == pj) cpos[gj] = e * e;
                    else { cd += e; cn += e * e * e; }
                }
            }
            cd += __shfl_xor(cd, 16); cn += __shfl_xor(cn, 16);
            cd += __shfl_xor(cd, 32); cn += __shfl_xor(cn, 32);
            if (quad == 0) { s_dc[gjl][wm] = cd; s_nc[gjl][wm] = cn; }
        }
    }

    __syncthreads();
    if (tid < BM) {
        pden[(size_t)bj * NROWS + i0 + tid] =
            s_dr[tid][0] + s_dr[tid][1] + s_dr[tid][2] + s_dr[tid][3];
        pnum[(size_t)bj * NROWS + i0 + tid] =
            s_nr[tid][0] + s_nr[tid][1] + s_nr[tid][2] + s_nr[tid][3];
    } else if (tid < 2 * BM && !diag) {
        int tt = tid - BM;
        pden[(size_t)bi * NROWS + j0 + tt] =
            s_dc[tt][0] + s_dc[tt][1] + s_dc[tt][2] + s_dc[tt][3];
        pnum[(size_t)bi * NROWS + j0 + tt] =
            s_nc[tt][0] + s_nc[tt][1] + s_nc[tt][2] + s_nc[tt][3];
    }
}

// -------- Kernel 3: fold partials -> loss; last block reduces to scalar --------
__global__ __launch_bounds__(256) void finalize_kernel(
    const float* __restrict__ pden, const float* __restrict__ pnum,
    const float* __restrict__ cpos, float* __restrict__ bpart,
    unsigned int* __restrict__ cnt, float* __restrict__ out)
{
    int i = blockIdx.x * 256 + threadIdx.x;    // RBLK*256 == NROWS
    float den = 0.f, num = 0.f;
    #pragma unroll 8
    for (int x = 0; x < NTIL; ++x) {
        den += pden[(size_t)x * NROWS + i];
        num += pnum[(size_t)x * NROWS + i];
    }
    float s = logf(1.0f + KNEG * (num / den) / cpos[i]);
    for (int m = 32; m; m >>= 1) s += __shfl_xor(s, m);
    __shared__ float wsum[4];
    if ((threadIdx.x & 63) == 0) wsum[threadIdx.x >> 6] = s;
    __syncthreads();
    if (threadIdx.x == 0) {
        atomicExch(&bpart[blockIdx.x], wsum[0] + wsum[1] + wsum[2] + wsum[3]);
        __threadfence();
        unsigned int old = atomicAdd(cnt, 1u);
        if (old == RBLK - 1) {
            float tot = 0.f;
            for (int b = 0; b < RBLK; ++b) tot += atomicAdd(&bpart[b], 0.0f);
            out[0] = tot / (float)NROWS;
        }
    }
}

extern "C" void kernel_launch(void* const* d_in, const int* in_sizes, int n_in,
                              void* d_out, int out_size, void* d_ws, size_t ws_size,
                              hipStream_t stream)
{
    const void* o1 = d_in[1];
    const void* o2 = d_in[2];

    // ws: pden 1MB | pnum 1MB | rn 32KB | cpos 32KB | bpart | cnt
    float* pden = (float*)d_ws;
    float* pnum = pden + (size_t)NTIL * NROWS;
    float* rn   = pnum + (size_t)NTIL * NROWS;
    float* cpos = rn + NROWS;
    float* bpart= cpos + NROWS;
    unsigned int* cnt = (unsigned int*)(bpart + RBLK);

    rownorm_kernel<<<NROWS / 4, 256, 0, stream>>>(o1, o2, rn, cnt);
    SupCon_hcl_49323404427556_kernel<<<TBLK, 1024, 0, stream>>>(o1, o2, rn, pden, pnum, cpos);
    finalize_kernel<<<RBLK, 256, 0, stream>>>(pden, pnum, cpos, bpart, cnt, (float*)d_out);
}